// Round 1
// baseline (72.461 us; speedup 1.0000x reference)
//
#include <hip/hip_runtime.h>

#define NPTS 8192
#define DIM 2
#define TILE 128
#define TT (NPTS / TILE)                 /* 64 tiles */
#define NPAIRS (TT * (TT + 1) / 2)       /* 2080 triangular tile-pairs */
#define MIN_DIST 0.1f

// Kernel 1: per-tile-pair proximity penalty partial sums.
// Block k handles tile-pair (bi, bj), bi <= bj. Thread t owns point
// i = bi*TILE + t and loops over the 128 j's of tile bj (wave-uniform
// addresses -> scalar loads, all data L1/L2-resident).
__global__ __launch_bounds__(TILE) void pair_tiles(const float2* __restrict__ P,
                                                   float* __restrict__ partial) {
    int k = blockIdx.x;

    // Decode triangular index k -> (bi, bj) with bi <= bj.
    // offset(bi) = bi*TT - bi*(bi-1)/2 pairs precede row bi.
    double Td = (double)TT;
    int bi = (int)((2.0 * Td + 1.0 -
                    sqrt((2.0 * Td + 1.0) * (2.0 * Td + 1.0) - 8.0 * (double)k)) * 0.5);
    if (bi < 0) bi = 0;
    if (bi >= TT) bi = TT - 1;
    while (bi > 0 && (bi * TT - bi * (bi - 1) / 2) > k) --bi;
    while (((bi + 1) * TT - (bi + 1) * bi / 2) <= k) ++bi;
    int bj = bi + (k - (bi * TT - bi * (bi - 1) / 2));

    int tid = threadIdx.x;
    float2 pi = P[bi * TILE + tid];
    const float2* __restrict__ pj = P + bj * TILE;

    float acc = 0.0f;
    if (bi == bj) {
        // Diagonal tile: full 128x128 minus the i==j diagonal, halved
        // (each unordered pair appears as (i,j) and (j,i) with equal d).
#pragma unroll 8
        for (int j = 0; j < TILE; ++j) {
            float2 q = pj[j];
            float dx = pi.x - q.x;
            float dy = pi.y - q.y;
            float d2 = fmaf(dy, dy, dx * dx);
            float s = __builtin_amdgcn_sqrtf(d2);
            float t = fmaxf(MIN_DIST - s, 0.0f);
            t = (j == tid) ? 0.0f : t;
            acc = fmaf(t, t, acc);
        }
        acc *= 0.5f;
    } else {
#pragma unroll 8
        for (int j = 0; j < TILE; ++j) {
            float2 q = pj[j];
            float dx = pi.x - q.x;
            float dy = pi.y - q.y;
            float d2 = fmaf(dy, dy, dx * dx);
            float s = __builtin_amdgcn_sqrtf(d2);
            float t = fmaxf(MIN_DIST - s, 0.0f);
            acc = fmaf(t, t, acc);
        }
    }

    // wave (64) reduce, then cross-wave via LDS
    for (int off = 32; off > 0; off >>= 1)
        acc += __shfl_down(acc, off, 64);
    __shared__ float wsum[TILE / 64];
    int wave = tid >> 6;
    int lane = tid & 63;
    if (lane == 0) wsum[wave] = acc;
    __syncthreads();
    if (tid == 0) {
        float s = wsum[0];
#pragma unroll
        for (int w = 1; w < TILE / 64; ++w) s += wsum[w];
        partial[k] = s;
    }
}

// Kernel 2: MSE + final reduction of the 2080 penalty partials (double
// accumulation for the final sums; f32 per-thread partials are fine).
__global__ __launch_bounds__(1024) void finalize(const float* __restrict__ pred,
                                                 const float* __restrict__ targ,
                                                 const float* __restrict__ partial,
                                                 float* __restrict__ out) {
    int tid = threadIdx.x;

    float mse = 0.0f;
    for (int idx = tid; idx < NPTS * DIM; idx += 1024) {
        float d = pred[idx] - targ[idx];
        mse = fmaf(d, d, mse);
    }
    double pen = 0.0;
    for (int idx = tid; idx < NPAIRS; idx += 1024)
        pen += (double)partial[idx];

    double v = (double)mse;
    for (int off = 32; off > 0; off >>= 1) {
        v += __shfl_down(v, off, 64);
        pen += __shfl_down(pen, off, 64);
    }
    __shared__ double sm[1024 / 64];
    __shared__ double sp[1024 / 64];
    int wave = tid >> 6;
    int lane = tid & 63;
    if (lane == 0) { sm[wave] = v; sp[wave] = pen; }
    __syncthreads();
    if (tid == 0) {
        double tv = 0.0, tp = 0.0;
#pragma unroll
        for (int w = 0; w < 1024 / 64; ++w) { tv += sm[w]; tp += sp[w]; }
        out[0] = (float)(tv / (double)(NPTS * DIM) + tp);
    }
}

extern "C" void kernel_launch(void* const* d_in, const int* in_sizes, int n_in,
                              void* d_out, int out_size, void* d_ws, size_t ws_size,
                              hipStream_t stream) {
    const float* pred = (const float*)d_in[0];
    const float* targ = (const float*)d_in[1];
    float* partial = (float*)d_ws;   // NPAIRS floats = 8320 B of scratch

    pair_tiles<<<NPAIRS, TILE, 0, stream>>>((const float2*)pred, partial);
    finalize<<<1, 1024, 0, stream>>>(pred, targ, partial, (float*)d_out);
}

// Round 2
// 67.390 us; speedup vs baseline: 1.0752x; 1.0752x over previous
//
#include <hip/hip_runtime.h>

#define NPTS 8192
#define TILE 128
#define TT (NPTS / TILE)            /* 64 row/col tiles           */
#define NPAIRS (TT * (TT + 1) / 2)  /* 2080 triangular tile pairs */
#define MIN_DIST 0.1f

// Fused kernel: proximity-penalty tile pairs + MSE partials.
// Block k handles tile pair (bi, bj), bi <= bj; blocks k<32 additionally
// compute a slice of the MSE. One float partial per block -> d_ws.
__global__ __launch_bounds__(TILE) void pair_tiles(const float2* __restrict__ P,
                                                   const float* __restrict__ pred,
                                                   const float* __restrict__ targ,
                                                   float* __restrict__ partial) {
    int k = blockIdx.x;

    // Triangular decode k -> (bi, bj) in integer/f32 (no f64), then fix up.
    int bi = (int)(((float)(2 * TT + 1) -
                    sqrtf((float)((2 * TT + 1) * (2 * TT + 1) - 8 * k))) * 0.5f);
    bi = min(max(bi, 0), TT - 1);
    while (bi > 0 && (bi * TT - bi * (bi - 1) / 2) > k) --bi;
    while (((bi + 1) * TT - (bi + 1) * bi / 2) <= k) ++bi;
    int bj = bi + (k - (bi * TT - bi * (bi - 1) / 2));
    // Force SGPR so the inner-loop loads are provably wave-uniform (s_load).
    bi = __builtin_amdgcn_readfirstlane(bi);
    bj = __builtin_amdgcn_readfirstlane(bj);

    int tid = threadIdx.x;
    float2 pi = P[bi * TILE + tid];
    // Two points per float4: (x0,y0,x1,y1). Uniform address -> scalar loads.
    const float4* __restrict__ q4 = (const float4*)(P + bj * TILE);

    float acc = 0.0f;
    if (bi == bj) {
        // Diagonal tile: all ordered pairs minus i==j, halved afterwards.
#pragma unroll 8
        for (int j = 0; j < TILE / 2; ++j) {
            float4 q = q4[j];
            float dx0 = pi.x - q.x, dy0 = pi.y - q.y;
            float dx1 = pi.x - q.z, dy1 = pi.y - q.w;
            float d20 = fmaf(dy0, dy0, dx0 * dx0);
            float d21 = fmaf(dy1, dy1, dx1 * dx1);
            float t0 = fmaxf(MIN_DIST - __builtin_amdgcn_sqrtf(d20), 0.0f);
            float t1 = fmaxf(MIN_DIST - __builtin_amdgcn_sqrtf(d21), 0.0f);
            t0 = (2 * j == tid) ? 0.0f : t0;
            t1 = (2 * j + 1 == tid) ? 0.0f : t1;
            acc = fmaf(t0, t0, acc);
            acc = fmaf(t1, t1, acc);
        }
        acc *= 0.5f;
    } else {
#pragma unroll 8
        for (int j = 0; j < TILE / 2; ++j) {
            float4 q = q4[j];
            float dx0 = pi.x - q.x, dy0 = pi.y - q.y;
            float dx1 = pi.x - q.z, dy1 = pi.y - q.w;
            float d20 = fmaf(dy0, dy0, dx0 * dx0);
            float d21 = fmaf(dy1, dy1, dx1 * dx1);
            float t0 = fmaxf(MIN_DIST - __builtin_amdgcn_sqrtf(d20), 0.0f);
            float t1 = fmaxf(MIN_DIST - __builtin_amdgcn_sqrtf(d21), 0.0f);
            acc = fmaf(t0, t0, acc);
            acc = fmaf(t1, t1, acc);
        }
    }

    // MSE slice: blocks 0..31, one float4 (4 elements) per thread = 16384 elems.
    if (k < 32) {
        int idx = k * TILE + tid;  // float4 index, 0..4095
        float4 p = ((const float4*)pred)[idx];
        float4 t = ((const float4*)targ)[idx];
        float m = 0.0f;
        float d0 = p.x - t.x, d1 = p.y - t.y, d2 = p.z - t.z, d3 = p.w - t.w;
        m = fmaf(d0, d0, m);
        m = fmaf(d1, d1, m);
        m = fmaf(d2, d2, m);
        m = fmaf(d3, d3, m);
        acc = fmaf(m, 1.0f / (float)(NPTS * 2), acc);
    }

    // wave (64) reduce, then cross-wave via LDS
    for (int off = 32; off > 0; off >>= 1)
        acc += __shfl_down(acc, off, 64);
    __shared__ float wsum[TILE / 64];
    int wave = tid >> 6;
    int lane = tid & 63;
    if (lane == 0) wsum[wave] = acc;
    __syncthreads();
    if (tid == 0) {
        float s = wsum[0];
#pragma unroll
        for (int w = 1; w < TILE / 64; ++w) s += wsum[w];
        partial[k] = s;
    }
}

// Final reduction: 2080 partials -> out[0], double accumulation.
__global__ __launch_bounds__(1024) void finalize(const float* __restrict__ partial,
                                                 float* __restrict__ out) {
    int tid = threadIdx.x;
    double s = 0.0;
    for (int i = tid; i < NPAIRS; i += 1024) s += (double)partial[i];

    for (int off = 32; off > 0; off >>= 1) s += __shfl_down(s, off, 64);
    __shared__ double sm[1024 / 64];
    int wave = tid >> 6;
    int lane = tid & 63;
    if (lane == 0) sm[wave] = s;
    __syncthreads();
    if (tid == 0) {
        double tot = 0.0;
#pragma unroll
        for (int w = 0; w < 1024 / 64; ++w) tot += sm[w];
        out[0] = (float)tot;
    }
}

extern "C" void kernel_launch(void* const* d_in, const int* in_sizes, int n_in,
                              void* d_out, int out_size, void* d_ws, size_t ws_size,
                              hipStream_t stream) {
    const float* pred = (const float*)d_in[0];
    const float* targ = (const float*)d_in[1];
    float* partial = (float*)d_ws;  // NPAIRS floats = 8320 B of scratch

    pair_tiles<<<NPAIRS, TILE, 0, stream>>>((const float2*)pred, pred, targ, partial);
    finalize<<<1, 1024, 0, stream>>>(partial, (float*)d_out);
}